// Round 1
// baseline (1663.919 us; speedup 1.0000x reference)
//
#include <hip/hip_runtime.h>
#include <math.h>

#define T_TOK 4096
#define H_DIM 1024
#define I_DIM 4096
#define E_NUM 8
#define KEI   32768   // E_NUM * I_DIM

typedef short s16x8 __attribute__((ext_vector_type(8)));
typedef float f32x4 __attribute__((ext_vector_type(4)));

// ---------- helpers ----------

__device__ __forceinline__ short f2b(float f) {
  // round-to-nearest-even fp32 -> bf16 bits (no NaN inputs here)
  union { float f; unsigned u; } v; v.f = f;
  unsigned r = v.u + 0x7fffu + ((v.u >> 16) & 1u);
  return (short)(r >> 16);
}

__device__ __forceinline__ void gld_lds16(short* lds, const short* g) {
  // async 16B global -> LDS. LDS dest is wave-uniform base + lane*16.
  __builtin_amdgcn_global_load_lds(
      (const __attribute__((address_space(1))) void*)g,
      (__attribute__((address_space(3))) void*)lds, 16, 0, 0);
}

// ---------- gate: softmax(x @ Wg^T) ----------
// one wave per token
__global__ __launch_bounds__(256) void gate_kernel(
    const float* __restrict__ x, const float* __restrict__ Wg,
    float* __restrict__ gate)
{
  int t = blockIdx.x * 4 + (threadIdx.x >> 6);
  int lane = threadIdx.x & 63;
  const float* xr = x + (size_t)t * H_DIM;
  float acc[E_NUM];
#pragma unroll
  for (int e = 0; e < E_NUM; ++e) acc[e] = 0.f;
  for (int j = 0; j < H_DIM / 64; ++j) {
    float xv = xr[lane + j * 64];
#pragma unroll
    for (int e = 0; e < E_NUM; ++e)
      acc[e] += xv * Wg[e * H_DIM + lane + j * 64];
  }
#pragma unroll
  for (int e = 0; e < E_NUM; ++e)
    for (int s = 32; s > 0; s >>= 1)
      acc[e] += __shfl_xor(acc[e], s, 64);
  if (lane == 0) {
    float mx = acc[0];
#pragma unroll
    for (int e = 1; e < E_NUM; ++e) mx = fmaxf(mx, acc[e]);
    float sum = 0.f, ex[E_NUM];
#pragma unroll
    for (int e = 0; e < E_NUM; ++e) { ex[e] = expf(acc[e] - mx); sum += ex[e]; }
    float inv = 1.f / sum;
#pragma unroll
    for (int e = 0; e < E_NUM; ++e) gate[t * E_NUM + e] = ex[e] * inv;
  }
}

// ---------- x fp32 -> bf16 ----------
__global__ __launch_bounds__(256) void convert_x_kernel(
    const float* __restrict__ x, short* __restrict__ xb)
{
  int idx = (blockIdx.x * 256 + threadIdx.x) * 4;
  float4 v = *(const float4*)(x + idx);
  short4 o;
  o.x = f2b(v.x); o.y = f2b(v.y); o.z = f2b(v.z); o.w = f2b(v.w);
  *(short4*)(xb + idx) = o;
}

// ---------- W1 [E][H][I] fp32 -> W1t [E][I][H] bf16 (transpose) ----------
__global__ __launch_bounds__(256) void trans_w1_kernel(
    const float* __restrict__ W1, short* __restrict__ W1t)
{
  __shared__ short tile[64][65];
  int e = blockIdx.z;
  int i0 = blockIdx.x * 64, h0 = blockIdx.y * 64;
  int tid = threadIdx.x, c = tid & 63, r0 = tid >> 6;
  const float* src = W1 + ((size_t)e * H_DIM + h0) * I_DIM + i0;
#pragma unroll
  for (int j = 0; j < 16; ++j) {
    int r = j * 4 + r0;                       // h offset
    tile[r][c] = f2b(src[(size_t)r * I_DIM + c]);
  }
  __syncthreads();
  short* dst = W1t + ((size_t)e * I_DIM + i0) * H_DIM + h0;
#pragma unroll
  for (int j = 0; j < 16; ++j) {
    int r = j * 4 + r0;                       // i offset
    dst[(size_t)r * H_DIM + c] = tile[c][r];
  }
}

// ---------- W2 [E][I][H] fp32 -> W2t [H][E*I] bf16 (transpose) ----------
__global__ __launch_bounds__(256) void trans_w2_kernel(
    const float* __restrict__ W2, short* __restrict__ W2t)
{
  __shared__ short tile[64][65];
  int e = blockIdx.z;
  int i0 = blockIdx.x * 64, h0 = blockIdx.y * 64;
  int tid = threadIdx.x, c = tid & 63, r0 = tid >> 6;
  const float* src = W2 + ((size_t)e * I_DIM + i0) * H_DIM + h0;
#pragma unroll
  for (int j = 0; j < 16; ++j) {
    int r = j * 4 + r0;                       // i offset
    tile[r][c] = f2b(src[(size_t)r * H_DIM + c]);
  }
  __syncthreads();
#pragma unroll
  for (int j = 0; j < 16; ++j) {
    int r = j * 4 + r0;                       // h offset
    W2t[(size_t)(h0 + r) * KEI + (size_t)e * I_DIM + i0 + c] = tile[c][r];
  }
}

// ---------- out init: out[t,h] = sum_e gate[t,e] * b2[e,h] ----------
__global__ __launch_bounds__(256) void out_init_kernel(
    const float* __restrict__ gate, const float* __restrict__ b2,
    float* __restrict__ out)
{
  int idx = blockIdx.x * 256 + threadIdx.x;
  int t = idx >> 10, h = idx & 1023;
  float v = 0.f;
#pragma unroll
  for (int e = 0; e < E_NUM; ++e)
    v += gate[t * E_NUM + e] * b2[e * H_DIM + h];
  out[idx] = v;
}

// ---------- 128x128 bf16 MFMA GEMM tile core ----------
// A: [*][lda] bf16 row-major, K contiguous; B: [*][ldb] bf16 row-major
// (N-major, K contiguous). LDS layout [g][row][8] so fragment ds_read_b128
// is 2-way bank-aliased (free) and global_load_lds lands contiguously.
__device__ __forceinline__ void gemm_tile(
    const short* __restrict__ A, const short* __restrict__ B,
    int lda, int ldb, int rowA, int rowB, int kBeg, int kEnd,
    short* As, short* Bs, f32x4 acc[4][4])
{
  const int tid  = threadIdx.x;
  const int wave = tid >> 6;
  const int lane = tid & 63;
  const int wm = wave >> 1, wn = wave & 1;
  const int g = lane >> 4, r16 = lane & 15;

  const int sg0 = wave >> 1;                 // staging k-group: 0,0,1,1
  const int sm  = ((wave & 1) << 6) + lane;  // staging row 0..127
  short* As0 = As + ((wave << 6)) * 8;
  short* As1 = As + ((wave << 6) + 256) * 8;
  short* Bs0 = Bs + ((wave << 6)) * 8;
  short* Bs1 = Bs + ((wave << 6) + 256) * 8;
  const short* Arow = A + (size_t)(rowA + sm) * lda;
  const short* Brow = B + (size_t)(rowB + sm) * ldb;

  for (int k0 = kBeg; k0 < kEnd; k0 += 32) {
    __syncthreads();
    gld_lds16(As0, Arow + k0 + sg0 * 8);
    gld_lds16(As1, Arow + k0 + (sg0 + 2) * 8);
    gld_lds16(Bs0, Brow + k0 + sg0 * 8);
    gld_lds16(Bs1, Brow + k0 + (sg0 + 2) * 8);
    __syncthreads();

    s16x8 af[4], bfr[4];
#pragma unroll
    for (int mi = 0; mi < 4; ++mi)
      af[mi] = *(const s16x8*)(As + ((g << 7) + (wm << 6) + (mi << 4) + r16) * 8);
#pragma unroll
    for (int ni = 0; ni < 4; ++ni)
      bfr[ni] = *(const s16x8*)(Bs + ((g << 7) + (wn << 6) + (ni << 4) + r16) * 8);
#pragma unroll
    for (int mi = 0; mi < 4; ++mi)
#pragma unroll
      for (int ni = 0; ni < 4; ++ni)
        acc[mi][ni] = __builtin_amdgcn_mfma_f32_16x16x32_bf16(
            af[mi], bfr[ni], acc[mi][ni], 0, 0, 0);
  }
}

// ---------- GEMM1: hg[t, e*I+n] = gelu(xb @ W1t[e]^T + b1[e]) * gate[t,e] ----------
__global__ __launch_bounds__(256) void gemm1_kernel(
    const short* __restrict__ xb, const short* __restrict__ W1t,
    const float* __restrict__ b1, const float* __restrict__ gate,
    short* __restrict__ hg)
{
  __shared__ __align__(16) short As[4096];
  __shared__ __align__(16) short Bs[4096];
  int bm = blockIdx.x, bn = blockIdx.y, e = blockIdx.z;

  f32x4 acc[4][4];
#pragma unroll
  for (int i = 0; i < 4; ++i)
#pragma unroll
    for (int j = 0; j < 4; ++j) acc[i][j] = (f32x4){0.f, 0.f, 0.f, 0.f};

  gemm_tile(xb, W1t + (size_t)e * I_DIM * H_DIM, H_DIM, H_DIM,
            bm * 128, bn * 128, 0, H_DIM, As, Bs, acc);

  const int wave = threadIdx.x >> 6, lane = threadIdx.x & 63;
  const int wm = wave >> 1, wn = wave & 1;
  const int g = lane >> 4, r16 = lane & 15;
  int row0 = bm * 128 + wm * 64;
  int col0 = bn * 128 + wn * 64;
#pragma unroll
  for (int mi = 0; mi < 4; ++mi) {
#pragma unroll
    for (int r = 0; r < 4; ++r) {
      int t = row0 + mi * 16 + g * 4 + r;
      float gt = gate[t * E_NUM + e];
#pragma unroll
      for (int ni = 0; ni < 4; ++ni) {
        int n = col0 + ni * 16 + r16;
        float v = acc[mi][ni][r] + b1[e * I_DIM + n];
        v = 0.5f * v * (1.0f + erff(v * 0.70710678118f));   // exact gelu
        hg[(size_t)t * KEI + (size_t)e * I_DIM + n] = f2b(v * gt);
      }
    }
  }
}

// ---------- GEMM2: out[t,h] += hg @ W2t^T  (split-K over z, atomic) ----------
__global__ __launch_bounds__(256) void gemm2_kernel(
    const short* __restrict__ hg, const short* __restrict__ W2t,
    float* __restrict__ out)
{
  __shared__ __align__(16) short As[4096];
  __shared__ __align__(16) short Bs[4096];
  int bn = blockIdx.x, bm = blockIdx.y, ks = blockIdx.z;

  f32x4 acc[4][4];
#pragma unroll
  for (int i = 0; i < 4; ++i)
#pragma unroll
    for (int j = 0; j < 4; ++j) acc[i][j] = (f32x4){0.f, 0.f, 0.f, 0.f};

  gemm_tile(hg, W2t, KEI, KEI, bm * 128, bn * 128,
            ks * (KEI / 4), (ks + 1) * (KEI / 4), As, Bs, acc);

  const int wave = threadIdx.x >> 6, lane = threadIdx.x & 63;
  const int wm = wave >> 1, wn = wave & 1;
  const int g = lane >> 4, r16 = lane & 15;
  int row0 = bm * 128 + wm * 64;
  int col0 = bn * 128 + wn * 64;
#pragma unroll
  for (int mi = 0; mi < 4; ++mi) {
#pragma unroll
    for (int r = 0; r < 4; ++r) {
      int t = row0 + mi * 16 + g * 4 + r;
#pragma unroll
      for (int ni = 0; ni < 4; ++ni) {
        int h = col0 + ni * 16 + r16;
        atomicAdd(&out[(size_t)t * H_DIM + h], acc[mi][ni][r]);
      }
    }
  }
}

// ---------- launch ----------
extern "C" void kernel_launch(void* const* d_in, const int* in_sizes, int n_in,
                              void* d_out, int out_size, void* d_ws, size_t ws_size,
                              hipStream_t stream) {
  const float* x  = (const float*)d_in[0];
  const float* Wg = (const float*)d_in[1];
  const float* W1 = (const float*)d_in[2];
  const float* b1 = (const float*)d_in[3];
  const float* W2 = (const float*)d_in[4];
  const float* b2 = (const float*)d_in[5];
  float* out = (float*)d_out;

  char* ws = (char*)d_ws;
  float* gate = (float*)ws;                               // 128 KiB
  short* xb   = (short*)(ws + 131072);                    // 8 MiB
  short* W1t  = (short*)(ws + 131072 + 8388608);          // 64 MiB
  short* W2t  = (short*)(ws + 131072 + 8388608 + 67108864);        // 64 MiB
  short* hg   = (short*)(ws + 131072 + 8388608 + 2 * 67108864);    // 256 MiB

  gate_kernel<<<T_TOK / 4, 256, 0, stream>>>(x, Wg, gate);
  convert_x_kernel<<<(T_TOK * H_DIM) / 1024, 256, 0, stream>>>(x, xb);
  trans_w1_kernel<<<dim3(I_DIM / 64, H_DIM / 64, E_NUM), 256, 0, stream>>>(W1, W1t);
  trans_w2_kernel<<<dim3(I_DIM / 64, H_DIM / 64, E_NUM), 256, 0, stream>>>(W2, W2t);
  out_init_kernel<<<(T_TOK * H_DIM) / 256, 256, 0, stream>>>(gate, b2, out);
  gemm1_kernel<<<dim3(T_TOK / 128, I_DIM / 128, E_NUM), 256, 0, stream>>>(
      xb, W1t, b1, gate, hg);
  gemm2_kernel<<<dim3(H_DIM / 128, T_TOK / 128, 4), 256, 0, stream>>>(
      hg, W2t, out);
}

// Round 2
// 1639.129 us; speedup vs baseline: 1.0151x; 1.0151x over previous
//
#include <hip/hip_runtime.h>
#include <math.h>

#define T_TOK 4096
#define H_DIM 1024
#define I_DIM 4096
#define E_NUM 8
#define KEI   32768   // E_NUM * I_DIM

typedef short s16x8 __attribute__((ext_vector_type(8)));
typedef float f32x4 __attribute__((ext_vector_type(4)));

// ---------- helpers ----------

__device__ __forceinline__ short f2b(float f) {
  // round-to-nearest-even fp32 -> bf16 bits (no NaN inputs here)
  union { float f; unsigned u; } v; v.f = f;
  unsigned r = v.u + 0x7fffu + ((v.u >> 16) & 1u);
  return (short)(r >> 16);
}

__device__ __forceinline__ void gld_lds16(short* lds, const short* g) {
  // async 16B global -> LDS. LDS dest is wave-uniform base + lane*16.
  __builtin_amdgcn_global_load_lds(
      (const __attribute__((address_space(1))) void*)g,
      (__attribute__((address_space(3))) void*)lds, 16, 0, 0);
}

// ---------- gate: softmax(x @ Wg^T) ----------
// one wave per token
__global__ __launch_bounds__(256) void gate_kernel(
    const float* __restrict__ x, const float* __restrict__ Wg,
    float* __restrict__ gate)
{
  int t = blockIdx.x * 4 + (threadIdx.x >> 6);
  int lane = threadIdx.x & 63;
  const float* xr = x + (size_t)t * H_DIM;
  float acc[E_NUM];
#pragma unroll
  for (int e = 0; e < E_NUM; ++e) acc[e] = 0.f;
  for (int j = 0; j < H_DIM / 64; ++j) {
    float xv = xr[lane + j * 64];
#pragma unroll
    for (int e = 0; e < E_NUM; ++e)
      acc[e] += xv * Wg[e * H_DIM + lane + j * 64];
  }
#pragma unroll
  for (int e = 0; e < E_NUM; ++e)
    for (int s = 32; s > 0; s >>= 1)
      acc[e] += __shfl_xor(acc[e], s, 64);
  if (lane == 0) {
    float mx = acc[0];
#pragma unroll
    for (int e = 1; e < E_NUM; ++e) mx = fmaxf(mx, acc[e]);
    float sum = 0.f, ex[E_NUM];
#pragma unroll
    for (int e = 0; e < E_NUM; ++e) { ex[e] = expf(acc[e] - mx); sum += ex[e]; }
    float inv = 1.f / sum;
#pragma unroll
    for (int e = 0; e < E_NUM; ++e) gate[t * E_NUM + e] = ex[e] * inv;
  }
}

// ---------- x fp32 -> bf16 ----------
__global__ __launch_bounds__(256) void convert_x_kernel(
    const float* __restrict__ x, short* __restrict__ xb)
{
  int idx = (blockIdx.x * 256 + threadIdx.x) * 4;
  float4 v = *(const float4*)(x + idx);
  short4 o;
  o.x = f2b(v.x); o.y = f2b(v.y); o.z = f2b(v.z); o.w = f2b(v.w);
  *(short4*)(xb + idx) = o;
}

// ---------- W1 [E][H][I] fp32 -> W1t [E][I][H] bf16 (transpose) ----------
__global__ __launch_bounds__(256) void trans_w1_kernel(
    const float* __restrict__ W1, short* __restrict__ W1t)
{
  __shared__ short tile[64][65];
  int e = blockIdx.z;
  int i0 = blockIdx.x * 64, h0 = blockIdx.y * 64;
  int tid = threadIdx.x, c = tid & 63, r0 = tid >> 6;
  const float* src = W1 + ((size_t)e * H_DIM + h0) * I_DIM + i0;
#pragma unroll
  for (int j = 0; j < 16; ++j) {
    int r = j * 4 + r0;                       // h offset
    tile[r][c] = f2b(src[(size_t)r * I_DIM + c]);
  }
  __syncthreads();
  short* dst = W1t + ((size_t)e * I_DIM + i0) * H_DIM + h0;
#pragma unroll
  for (int j = 0; j < 16; ++j) {
    int r = j * 4 + r0;                       // i offset
    dst[(size_t)r * H_DIM + c] = tile[c][r];
  }
}

// ---------- W2 [E][I][H] fp32 -> W2t [H][E*I] bf16 (transpose) ----------
__global__ __launch_bounds__(256) void trans_w2_kernel(
    const float* __restrict__ W2, short* __restrict__ W2t)
{
  __shared__ short tile[64][65];
  int e = blockIdx.z;
  int i0 = blockIdx.x * 64, h0 = blockIdx.y * 64;
  int tid = threadIdx.x, c = tid & 63, r0 = tid >> 6;
  const float* src = W2 + ((size_t)e * I_DIM + i0) * H_DIM + h0;
#pragma unroll
  for (int j = 0; j < 16; ++j) {
    int r = j * 4 + r0;                       // i offset
    tile[r][c] = f2b(src[(size_t)r * H_DIM + c]);
  }
  __syncthreads();
#pragma unroll
  for (int j = 0; j < 16; ++j) {
    int r = j * 4 + r0;                       // h offset
    W2t[(size_t)(h0 + r) * KEI + (size_t)e * I_DIM + i0 + c] = tile[c][r];
  }
}

// ---------- out init: out[t,h] = sum_e gate[t,e] * b2[e,h] ----------
__global__ __launch_bounds__(256) void out_init_kernel(
    const float* __restrict__ gate, const float* __restrict__ b2,
    float* __restrict__ out)
{
  int idx = blockIdx.x * 256 + threadIdx.x;
  int t = idx >> 10, h = idx & 1023;
  float v = 0.f;
#pragma unroll
  for (int e = 0; e < E_NUM; ++e)
    v += gate[t * E_NUM + e] * b2[e * H_DIM + h];
  out[idx] = v;
}

// ---------- 128x128 bf16 MFMA GEMM tile core (gemm1) ----------
__device__ __forceinline__ void gemm_tile(
    const short* __restrict__ A, const short* __restrict__ B,
    int lda, int ldb, int rowA, int rowB, int kBeg, int kEnd,
    short* As, short* Bs, f32x4 acc[4][4])
{
  const int tid  = threadIdx.x;
  const int wave = tid >> 6;
  const int lane = tid & 63;
  const int wm = wave >> 1, wn = wave & 1;
  const int g = lane >> 4, r16 = lane & 15;

  const int sg0 = wave >> 1;                 // staging k-group: 0,0,1,1
  const int sm  = ((wave & 1) << 6) + lane;  // staging row 0..127
  short* As0 = As + ((wave << 6)) * 8;
  short* As1 = As + ((wave << 6) + 256) * 8;
  short* Bs0 = Bs + ((wave << 6)) * 8;
  short* Bs1 = Bs + ((wave << 6) + 256) * 8;
  const short* Arow = A + (size_t)(rowA + sm) * lda;
  const short* Brow = B + (size_t)(rowB + sm) * ldb;

  for (int k0 = kBeg; k0 < kEnd; k0 += 32) {
    __syncthreads();
    gld_lds16(As0, Arow + k0 + sg0 * 8);
    gld_lds16(As1, Arow + k0 + (sg0 + 2) * 8);
    gld_lds16(Bs0, Brow + k0 + sg0 * 8);
    gld_lds16(Bs1, Brow + k0 + (sg0 + 2) * 8);
    __syncthreads();

    s16x8 af[4], bfr[4];
#pragma unroll
    for (int mi = 0; mi < 4; ++mi)
      af[mi] = *(const s16x8*)(As + ((g << 7) + (wm << 6) + (mi << 4) + r16) * 8);
#pragma unroll
    for (int ni = 0; ni < 4; ++ni)
      bfr[ni] = *(const s16x8*)(Bs + ((g << 7) + (wn << 6) + (ni << 4) + r16) * 8);
#pragma unroll
    for (int mi = 0; mi < 4; ++mi)
#pragma unroll
      for (int ni = 0; ni < 4; ++ni)
        acc[mi][ni] = __builtin_amdgcn_mfma_f32_16x16x32_bf16(
            af[mi], bfr[ni], acc[mi][ni], 0, 0, 0);
  }
}

// ---------- GEMM1: hg[t, e*I+n] = gelu(xb @ W1t[e]^T + b1[e]) * gate[t,e] ----------
__global__ __launch_bounds__(256) void gemm1_kernel(
    const short* __restrict__ xb, const short* __restrict__ W1t,
    const float* __restrict__ b1, const float* __restrict__ gate,
    short* __restrict__ hg)
{
  __shared__ __align__(16) short As[4096];
  __shared__ __align__(16) short Bs[4096];
  int bm = blockIdx.x, bn = blockIdx.y, e = blockIdx.z;

  f32x4 acc[4][4];
#pragma unroll
  for (int i = 0; i < 4; ++i)
#pragma unroll
    for (int j = 0; j < 4; ++j) acc[i][j] = (f32x4){0.f, 0.f, 0.f, 0.f};

  gemm_tile(xb, W1t + (size_t)e * I_DIM * H_DIM, H_DIM, H_DIM,
            bm * 128, bn * 128, 0, H_DIM, As, Bs, acc);

  const int wave = threadIdx.x >> 6, lane = threadIdx.x & 63;
  const int wm = wave >> 1, wn = wave & 1;
  const int g = lane >> 4, r16 = lane & 15;
  int row0 = bm * 128 + wm * 64;
  int col0 = bn * 128 + wn * 64;
#pragma unroll
  for (int mi = 0; mi < 4; ++mi) {
#pragma unroll
    for (int r = 0; r < 4; ++r) {
      int t = row0 + mi * 16 + g * 4 + r;
      float gt = gate[t * E_NUM + e];
#pragma unroll
      for (int ni = 0; ni < 4; ++ni) {
        int n = col0 + ni * 16 + r16;
        float v = acc[mi][ni][r] + b1[e * I_DIM + n];
        v = 0.5f * v * (1.0f + erff(v * 0.70710678118f));   // exact gelu
        hg[(size_t)t * KEI + (size_t)e * I_DIM + n] = f2b(v * gt);
      }
    }
  }
}

// ---------- GEMM2 v2: out[t,h] += hg @ W2t^T ----------
// 512 threads (8 waves), tile BM=128 x BN=512, wave grid 2x4 (64x128 each),
// split-K=4. A (hg, 256 MB) is re-read only 2x instead of 8x.
__global__ __launch_bounds__(512, 2) void gemm2_kernel(
    const short* __restrict__ hg, const short* __restrict__ W2t,
    float* __restrict__ out)
{
  __shared__ __align__(16) short As[128 * 32];   // 8 KiB
  __shared__ __align__(16) short Bs[512 * 32];   // 32 KiB

  int nblk = blockIdx.x;
  int bn = nblk & 1;          // 2 col tiles of 512
  int q  = nblk >> 1;
  int bm = q & 31;            // 32 row tiles of 128
  int ks = q >> 5;            // split-K 0..3

  const int tid  = threadIdx.x;
  const int wave = tid >> 6;     // 0..7
  const int lane = tid & 63;
  const int wm = wave >> 2;      // 0..1  (row half)
  const int wn = wave & 3;       // 0..3  (col quarter)
  const int g = lane >> 4, r16 = lane & 15;

  f32x4 acc[4][8];
#pragma unroll
  for (int i = 0; i < 4; ++i)
#pragma unroll
    for (int j = 0; j < 8; ++j) acc[i][j] = (f32x4){0.f, 0.f, 0.f, 0.f};

  // --- staging assignment ---
  // A: 128 rows x 32 k = 8 chunks (g in 0..3, rowhalf in 0..1); 1 per wave.
  const int sgA = wave >> 1;            // k-group 0..3
  const int rhA = wave & 1;             // row half
  short* AsDst = As + (sgA * 128 + rhA * 64) * 8;
  const short* Asrc = hg + (size_t)(bm * 128 + rhA * 64 + lane) * KEI + sgA * 8;

  // B: 512 cols x 32 k = 32 chunks; wave w, round r: g = w>>1, cb = (w&1)*4+r.
  const int sgB = wave >> 1;
  short* BsDst[4];
  const short* Bsrc[4];
#pragma unroll
  for (int r = 0; r < 4; ++r) {
    int cb = (wave & 1) * 4 + r;        // col block 0..7
    BsDst[r] = Bs + (sgB * 512 + cb * 64) * 8;
    Bsrc[r]  = W2t + (size_t)(bn * 512 + cb * 64 + lane) * KEI + sgB * 8;
  }

  int kBeg = ks * (KEI / 4), kEnd = kBeg + (KEI / 4);
  for (int k0 = kBeg; k0 < kEnd; k0 += 32) {
    __syncthreads();
    gld_lds16(AsDst, Asrc + k0);
#pragma unroll
    for (int r = 0; r < 4; ++r)
      gld_lds16(BsDst[r], Bsrc[r] + k0);
    __syncthreads();

    s16x8 af[4], bfr[8];
#pragma unroll
    for (int mi = 0; mi < 4; ++mi)
      af[mi] = *(const s16x8*)(As + ((g << 7) + (wm << 6) + (mi << 4) + r16) * 8);
#pragma unroll
    for (int ni = 0; ni < 8; ++ni)
      bfr[ni] = *(const s16x8*)(Bs + ((g << 9) + (wn << 7) + (ni << 4) + r16) * 8);
#pragma unroll
    for (int mi = 0; mi < 4; ++mi)
#pragma unroll
      for (int ni = 0; ni < 8; ++ni)
        acc[mi][ni] = __builtin_amdgcn_mfma_f32_16x16x32_bf16(
            af[mi], bfr[ni], acc[mi][ni], 0, 0, 0);
  }

  int row0 = bm * 128 + wm * 64;
  int col0 = bn * 512 + wn * 128;
#pragma unroll
  for (int mi = 0; mi < 4; ++mi) {
#pragma unroll
    for (int r = 0; r < 4; ++r) {
      int t = row0 + mi * 16 + g * 4 + r;
#pragma unroll
      for (int ni = 0; ni < 8; ++ni) {
        int h = col0 + ni * 16 + r16;
        atomicAdd(&out[(size_t)t * H_DIM + h], acc[mi][ni][r]);
      }
    }
  }
}

// ---------- launch ----------
extern "C" void kernel_launch(void* const* d_in, const int* in_sizes, int n_in,
                              void* d_out, int out_size, void* d_ws, size_t ws_size,
                              hipStream_t stream) {
  const float* x  = (const float*)d_in[0];
  const float* Wg = (const float*)d_in[1];
  const float* W1 = (const float*)d_in[2];
  const float* b1 = (const float*)d_in[3];
  const float* W2 = (const float*)d_in[4];
  const float* b2 = (const float*)d_in[5];
  float* out = (float*)d_out;

  char* ws = (char*)d_ws;
  float* gate = (float*)ws;                               // 128 KiB
  short* xb   = (short*)(ws + 131072);                    // 8 MiB
  short* W1t  = (short*)(ws + 131072 + 8388608);          // 64 MiB
  short* W2t  = (short*)(ws + 131072 + 8388608 + 67108864);        // 64 MiB
  short* hg   = (short*)(ws + 131072 + 8388608 + 2 * 67108864);    // 256 MiB

  gate_kernel<<<T_TOK / 4, 256, 0, stream>>>(x, Wg, gate);
  convert_x_kernel<<<(T_TOK * H_DIM) / 1024, 256, 0, stream>>>(x, xb);
  trans_w1_kernel<<<dim3(I_DIM / 64, H_DIM / 64, E_NUM), 256, 0, stream>>>(W1, W1t);
  trans_w2_kernel<<<dim3(I_DIM / 64, H_DIM / 64, E_NUM), 256, 0, stream>>>(W2, W2t);
  out_init_kernel<<<(T_TOK * H_DIM) / 256, 256, 0, stream>>>(gate, b2, out);
  gemm1_kernel<<<dim3(T_TOK / 128, I_DIM / 128, E_NUM), 256, 0, stream>>>(
      xb, W1t, b1, gate, hg);
  gemm2_kernel<<<256, 512, 0, stream>>>(hg, W2t, out);
}

// Round 3
// 1281.730 us; speedup vs baseline: 1.2982x; 1.2788x over previous
//
#include <hip/hip_runtime.h>
#include <math.h>

#define T_TOK 4096
#define H_DIM 1024
#define I_DIM 4096
#define E_NUM 8
#define KEI   32768   // E_NUM * I_DIM

// Blocked K-panel layout for all bf16 staged matrices:
//   M[rb][kc][64][8]  (rb = row/64, kc = k/8)
// so one global_load_lds (64 lanes x 16B) is 1KB contiguous.

typedef short s16x8 __attribute__((ext_vector_type(8)));
typedef float f32x4 __attribute__((ext_vector_type(4)));

__device__ __forceinline__ short f2b(float f) {
  union { float f; unsigned u; } v; v.f = f;
  unsigned r = v.u + 0x7fffu + ((v.u >> 16) & 1u);
  return (short)(r >> 16);
}

__device__ __forceinline__ void gld_lds16(short* lds, const short* g) {
  __builtin_amdgcn_global_load_lds(
      (const __attribute__((address_space(1))) void*)g,
      (__attribute__((address_space(3))) void*)lds, 16, 0, 0);
}

// ---------- gate: softmax(x @ Wg^T), one wave per token ----------
__global__ __launch_bounds__(256) void gate_kernel(
    const float* __restrict__ x, const float* __restrict__ Wg,
    float* __restrict__ gate)
{
  int t = blockIdx.x * 4 + (threadIdx.x >> 6);
  int lane = threadIdx.x & 63;
  const float* xr = x + (size_t)t * H_DIM;
  float acc[E_NUM];
#pragma unroll
  for (int e = 0; e < E_NUM; ++e) acc[e] = 0.f;
  for (int j = 0; j < H_DIM / 64; ++j) {
    float xv = xr[lane + j * 64];
#pragma unroll
    for (int e = 0; e < E_NUM; ++e)
      acc[e] += xv * Wg[e * H_DIM + lane + j * 64];
  }
#pragma unroll
  for (int e = 0; e < E_NUM; ++e)
    for (int s = 32; s > 0; s >>= 1)
      acc[e] += __shfl_xor(acc[e], s, 64);
  if (lane == 0) {
    float mx = acc[0];
#pragma unroll
    for (int e = 1; e < E_NUM; ++e) mx = fmaxf(mx, acc[e]);
    float sum = 0.f, ex[E_NUM];
#pragma unroll
    for (int e = 0; e < E_NUM; ++e) { ex[e] = expf(acc[e] - mx); sum += ex[e]; }
    float inv = 1.f / sum;
#pragma unroll
    for (int e = 0; e < E_NUM; ++e) gate[t * E_NUM + e] = ex[e] * inv;
  }
}

// ---------- x fp32 -> xb blocked bf16 [64 rb][128 kc][64][8] ----------
__global__ __launch_bounds__(256) void convert_x_kernel(
    const float* __restrict__ x, short* __restrict__ xb)
{
  int rb = blockIdx.x;                     // token/64 block
  int t  = threadIdx.x & 63;
  int kq = threadIdx.x >> 6;               // 0..3
#pragma unroll
  for (int j = 0; j < 8; ++j) {
    int kc = blockIdx.y * 32 + kq + j * 4;
    const float* src = x + ((size_t)rb * 64 + t) * H_DIM + kc * 8;
    float4 a = *(const float4*)src;
    float4 b = *(const float4*)(src + 4);
    s16x8 v;
    v[0] = f2b(a.x); v[1] = f2b(a.y); v[2] = f2b(a.z); v[3] = f2b(a.w);
    v[4] = f2b(b.x); v[5] = f2b(b.y); v[6] = f2b(b.z); v[7] = f2b(b.w);
    *(s16x8*)(xb + ((size_t)rb * 128 + kc) * 512 + t * 8) = v;
  }
}

// ---------- W1 [E][H][I] fp32 -> W1t blocked [e][rb=i/64][kc=h/8][64][8] ----------
__global__ __launch_bounds__(256) void trans_w1_kernel(
    const float* __restrict__ W1, short* __restrict__ W1t)
{
  __shared__ short tile[64][65];           // [h][i]
  int e = blockIdx.z;
  int i0 = blockIdx.x * 64, h0 = blockIdx.y * 64;
  int tid = threadIdx.x, c = tid & 63, r0 = tid >> 6;
  const float* src = W1 + ((size_t)e * H_DIM + h0) * I_DIM + i0;
#pragma unroll
  for (int j = 0; j < 16; ++j) {
    int r = j * 4 + r0;                    // h offset
    tile[r][c] = f2b(src[(size_t)r * I_DIM + c]);
  }
  __syncthreads();
  int i = tid & 63, kq = tid >> 6;
#pragma unroll
  for (int w = 0; w < 2; ++w) {
    int kcl = kq + w * 4;                  // 0..7
    s16x8 v;
#pragma unroll
    for (int j = 0; j < 8; ++j) v[j] = tile[kcl * 8 + j][i];
    size_t chunk = (size_t)e * 8192 + (size_t)blockIdx.x * 128 + (h0 >> 3) + kcl;
    *(s16x8*)(W1t + chunk * 512 + i * 8) = v;
  }
}

// ---------- W2 [E][I][H] fp32 -> W2t blocked [rb=h/64][kc=(e*I+i)/8][64][8] ----------
__global__ __launch_bounds__(256) void trans_w2_kernel(
    const float* __restrict__ W2, short* __restrict__ W2t)
{
  __shared__ short tile[64][65];           // [i][h]
  int e = blockIdx.z;
  int i0 = blockIdx.x * 64, h0 = blockIdx.y * 64;
  int tid = threadIdx.x, c = tid & 63, r0 = tid >> 6;
  const float* src = W2 + ((size_t)e * I_DIM + i0) * H_DIM + h0;
#pragma unroll
  for (int j = 0; j < 16; ++j) {
    int r = j * 4 + r0;                    // i offset
    tile[r][c] = f2b(src[(size_t)r * H_DIM + c]);
  }
  __syncthreads();
  int h = tid & 63, kq = tid >> 6;
#pragma unroll
  for (int w = 0; w < 2; ++w) {
    int kcl = kq + w * 4;                  // 0..7
    s16x8 v;
#pragma unroll
    for (int j = 0; j < 8; ++j) v[j] = tile[kcl * 8 + j][h];
    size_t chunk = (size_t)blockIdx.y * 4096 + e * 512 + (i0 >> 3) + kcl;
    *(s16x8*)(W2t + chunk * 512 + h * 8) = v;
  }
}

// ---------- out init: out[t,h] = sum_e gate[t,e] * b2[e,h] ----------
__global__ __launch_bounds__(256) void out_init_kernel(
    const float* __restrict__ gate, const float* __restrict__ b2,
    float* __restrict__ out)
{
  int idx = blockIdx.x * 256 + threadIdx.x;
  int t = idx >> 10, h = idx & 1023;
  float v = 0.f;
#pragma unroll
  for (int e = 0; e < E_NUM; ++e)
    v += gate[t * E_NUM + e] * b2[e * H_DIM + h];
  out[idx] = v;
}

// ---------- GEMM1: hg = gelu(xb @ W1t[e]^T + b1)*gate, 128x128, dbuf ----------
__global__ __launch_bounds__(256) void gemm1_kernel(
    const short* __restrict__ xb, const short* __restrict__ W1t,
    const float* __restrict__ b1, const float* __restrict__ gate,
    short* __restrict__ hg)
{
  __shared__ __align__(16) short As[2 * 4096];   // [buf][kcl4][128][8]
  __shared__ __align__(16) short Bs[2 * 4096];
  int bm = blockIdx.x, bn = blockIdx.y, e = blockIdx.z;

  const int tid = threadIdx.x, wave = tid >> 6, lane = tid & 63;
  const int wm = wave >> 1, wn = wave & 1;
  const int g = lane >> 4, r16 = lane & 15;

  f32x4 acc[4][4];
#pragma unroll
  for (int i = 0; i < 4; ++i)
#pragma unroll
    for (int j = 0; j < 4; ++j) acc[i][j] = (f32x4){0.f, 0.f, 0.f, 0.f};

  // staging: wave w -> chunks (rbl=w&1, kcl=w>>1) and (rbl, kcl+2) for A and B
  const int rbl = wave & 1, kq = wave >> 1;     // kq in {0,1}
  short* AsD0 = As + (kq * 128 + rbl * 64) * 8;
  short* AsD1 = As + ((kq + 2) * 128 + rbl * 64) * 8;
  short* BsD0 = Bs + (kq * 128 + rbl * 64) * 8;
  short* BsD1 = Bs + ((kq + 2) * 128 + rbl * 64) * 8;
  const short* Asrc = xb + (((size_t)(bm * 2 + rbl) * 128) + kq) * 512 + lane * 8;
  const short* Bsrc = W1t + (size_t)e * (8192 * 512)
                    + (((size_t)(bn * 2 + rbl) * 128) + kq) * 512 + lane * 8;

  // prologue: stage k-tile 0 into buf 0
  gld_lds16(AsD0, Asrc);
  gld_lds16(AsD1, Asrc + 1024);
  gld_lds16(BsD0, Bsrc);
  gld_lds16(BsD1, Bsrc + 1024);

  for (int k0 = 0; k0 < H_DIM; k0 += 32) {
    int cur = (k0 >> 5) & 1;
    __syncthreads();                       // drains prefetch issued last iter
    if (k0 + 32 < H_DIM) {
      int nb = cur ^ 1;
      size_t soff = ((size_t)(k0 >> 3) + 4) * 512;
      gld_lds16(AsD0 + nb * 4096, Asrc + soff);
      gld_lds16(AsD1 + nb * 4096, Asrc + soff + 1024);
      gld_lds16(BsD0 + nb * 4096, Bsrc + soff);
      gld_lds16(BsD1 + nb * 4096, Bsrc + soff + 1024);
    }
    const short* Ab = As + cur * 4096;
    const short* Bb = Bs + cur * 4096;
    s16x8 af[4], bfr[4];
#pragma unroll
    for (int mi = 0; mi < 4; ++mi)
      af[mi] = *(const s16x8*)(Ab + ((g << 7) + (wm << 6) + (mi << 4) + r16) * 8);
#pragma unroll
    for (int ni = 0; ni < 4; ++ni)
      bfr[ni] = *(const s16x8*)(Bb + ((g << 7) + (wn << 6) + (ni << 4) + r16) * 8);
#pragma unroll
    for (int mi = 0; mi < 4; ++mi)
#pragma unroll
      for (int ni = 0; ni < 4; ++ni)
        acc[mi][ni] = __builtin_amdgcn_mfma_f32_16x16x32_bf16(
            af[mi], bfr[ni], acc[mi][ni], 0, 0, 0);
  }

  int row0 = bm * 128 + wm * 64;
  int col0 = bn * 128 + wn * 64;
#pragma unroll
  for (int mi = 0; mi < 4; ++mi) {
#pragma unroll
    for (int r = 0; r < 4; ++r) {
      int t = row0 + mi * 16 + g * 4 + r;
      float gt = gate[t * E_NUM + e];
      size_t tbase = ((size_t)(t >> 6) * 4096) * 512 + (size_t)(t & 63) * 8;
#pragma unroll
      for (int ni = 0; ni < 4; ++ni) {
        int n = col0 + ni * 16 + r16;
        int k = e * I_DIM + n;
        float v = acc[mi][ni][r] + b1[e * I_DIM + n];
        v = 0.5f * v * (1.0f + erff(v * 0.70710678118f));   // exact gelu
        hg[tbase + (size_t)(k >> 3) * 512 + (k & 7)] = f2b(v * gt);
      }
    }
  }
}

// ---------- GEMM2: out += hg @ W2t^T, 128x512, 8 waves, dbuf, split-K=4 ----------
__global__ __launch_bounds__(512) void gemm2_kernel(
    const short* __restrict__ hg, const short* __restrict__ W2t,
    float* __restrict__ out)
{
  __shared__ __align__(16) short As[2 * 4096];    // [buf][kcl4][128][8]   16 KiB
  __shared__ __align__(16) short Bs[2 * 16384];   // [buf][kcl4][512][8]   64 KiB

  int bn = blockIdx.x;        // 0..1
  int bm = blockIdx.y;        // 0..31
  int ks = blockIdx.z;        // 0..3

  const int tid = threadIdx.x, wave = tid >> 6, lane = tid & 63;
  const int wm = wave >> 2, wn = wave & 3;
  const int g = lane >> 4, r16 = lane & 15;

  f32x4 acc[4][8];
#pragma unroll
  for (int i = 0; i < 4; ++i)
#pragma unroll
    for (int j = 0; j < 8; ++j) acc[i][j] = (f32x4){0.f, 0.f, 0.f, 0.f};

  // staging: wave w -> A chunk (rbl=w&1, kcl=w>>1); B chunks (rbl=(w&1)*4+r, kcl=w>>1)
  const int rblA = wave & 1, kq = wave >> 1;      // kq 0..3
  short* AsD = As + (kq * 128 + rblA * 64) * 8;
  const short* Asrc = hg + (((size_t)(bm * 2 + rblA) * 4096) + kq) * 512 + lane * 8;
  short* BsD[4];
  const short* Bsrc[4];
#pragma unroll
  for (int r = 0; r < 4; ++r) {
    int rblB = (wave & 1) * 4 + r;
    BsD[r]  = Bs + (kq * 512 + rblB * 64) * 8;
    Bsrc[r] = W2t + (((size_t)(bn * 8 + rblB) * 4096) + kq) * 512 + lane * 8;
  }

  const int kBeg = ks * (KEI / 4), kEnd = kBeg + (KEI / 4);

  // prologue
  {
    size_t soff = (size_t)(kBeg >> 3) * 512;
    gld_lds16(AsD, Asrc + soff);
#pragma unroll
    for (int r = 0; r < 4; ++r) gld_lds16(BsD[r], Bsrc[r] + soff);
  }

  for (int k0 = kBeg; k0 < kEnd; k0 += 32) {
    int cur = ((k0 - kBeg) >> 5) & 1;
    __syncthreads();
    if (k0 + 32 < kEnd) {
      int nb = cur ^ 1;
      size_t soff = ((size_t)(k0 >> 3) + 4) * 512;
      gld_lds16(AsD + nb * 4096, Asrc + soff);
#pragma unroll
      for (int r = 0; r < 4; ++r) gld_lds16(BsD[r] + nb * 16384, Bsrc[r] + soff);
    }
    const short* Ab = As + cur * 4096;
    const short* Bb = Bs + cur * 16384;
    s16x8 af[4], bfr[8];
#pragma unroll
    for (int mi = 0; mi < 4; ++mi)
      af[mi] = *(const s16x8*)(Ab + ((g << 7) + (wm << 6) + (mi << 4) + r16) * 8);
#pragma unroll
    for (int ni = 0; ni < 8; ++ni)
      bfr[ni] = *(const s16x8*)(Bb + ((g << 9) + (wn << 7) + (ni << 4) + r16) * 8);
#pragma unroll
    for (int mi = 0; mi < 4; ++mi)
#pragma unroll
      for (int ni = 0; ni < 8; ++ni)
        acc[mi][ni] = __builtin_amdgcn_mfma_f32_16x16x32_bf16(
            af[mi], bfr[ni], acc[mi][ni], 0, 0, 0);
  }

  int row0 = bm * 128 + wm * 64;
  int col0 = bn * 512 + wn * 128;
#pragma unroll
  for (int mi = 0; mi < 4; ++mi) {
#pragma unroll
    for (int r = 0; r < 4; ++r) {
      int t = row0 + mi * 16 + g * 4 + r;
#pragma unroll
      for (int ni = 0; ni < 8; ++ni) {
        int h = col0 + ni * 16 + r16;
        atomicAdd(&out[(size_t)t * H_DIM + h], acc[mi][ni][r]);
      }
    }
  }
}

// ---------- launch ----------
extern "C" void kernel_launch(void* const* d_in, const int* in_sizes, int n_in,
                              void* d_out, int out_size, void* d_ws, size_t ws_size,
                              hipStream_t stream) {
  const float* x  = (const float*)d_in[0];
  const float* Wg = (const float*)d_in[1];
  const float* W1 = (const float*)d_in[2];
  const float* b1 = (const float*)d_in[3];
  const float* W2 = (const float*)d_in[4];
  const float* b2 = (const float*)d_in[5];
  float* out = (float*)d_out;

  char* ws = (char*)d_ws;
  float* gate = (float*)ws;                               // 128 KiB
  short* xb   = (short*)(ws + 131072);                    // 8 MiB  (blocked)
  short* W1t  = (short*)(ws + 131072 + 8388608);          // 64 MiB (blocked)
  short* W2t  = (short*)(ws + 131072 + 8388608 + 67108864);        // 64 MiB (blocked)
  short* hg   = (short*)(ws + 131072 + 8388608 + 2 * 67108864);    // 256 MiB (blocked)

  gate_kernel<<<T_TOK / 4, 256, 0, stream>>>(x, Wg, gate);
  convert_x_kernel<<<dim3(T_TOK / 64, 4), 256, 0, stream>>>(x, xb);
  trans_w1_kernel<<<dim3(I_DIM / 64, H_DIM / 64, E_NUM), 256, 0, stream>>>(W1, W1t);
  trans_w2_kernel<<<dim3(I_DIM / 64, H_DIM / 64, E_NUM), 256, 0, stream>>>(W2, W2t);
  out_init_kernel<<<(T_TOK * H_DIM) / 256, 256, 0, stream>>>(gate, b2, out);
  gemm1_kernel<<<dim3(T_TOK / 128, I_DIM / 128, E_NUM), 256, 0, stream>>>(
      xb, W1t, b1, gate, hg);
  gemm2_kernel<<<dim3(2, 32, 4), 512, 0, stream>>>(hg, W2t, out);
}

// Round 4
// 1089.390 us; speedup vs baseline: 1.5274x; 1.1766x over previous
//
#include <hip/hip_runtime.h>
#include <math.h>

#define T_TOK 4096
#define H_DIM 1024
#define I_DIM 4096
#define E_NUM 8
#define KEI   32768   // E_NUM * I_DIM

// Blocked K-panel layout for all bf16 staged matrices:
//   M[rb][kc][64][8]  (rb = row/64, kc = k/8)
// so one global_load_lds (64 lanes x 16B) is 1KB contiguous.

typedef short s16x8 __attribute__((ext_vector_type(8)));
typedef float f32x4 __attribute__((ext_vector_type(4)));

__device__ __forceinline__ short f2b(float f) {
  union { float f; unsigned u; } v; v.f = f;
  unsigned r = v.u + 0x7fffu + ((v.u >> 16) & 1u);
  return (short)(r >> 16);
}

__device__ __forceinline__ void gld_lds16(short* lds, const short* g) {
  __builtin_amdgcn_global_load_lds(
      (const __attribute__((address_space(1))) void*)g,
      (__attribute__((address_space(3))) void*)lds, 16, 0, 0);
}

// Branch-free exact-GELU via Abramowitz-Stegun 7.1.26 erf (|eps|<=1.5e-7).
// ~18 VALU ops vs ~70 for libm erff (which diverges on range branches).
__device__ __forceinline__ float gelu_f(float v) {
  float a = fabsf(v);
  float z = a * 0.70710678118f;
  float t = __builtin_amdgcn_rcpf(fmaf(0.3275911f, z, 1.0f));
  float p = fmaf(fmaf(fmaf(fmaf(1.061405429f, t, -1.453152027f), t,
              1.421413741f), t, -0.284496736f), t, 0.254829592f) * t;
  float e = __expf(-z * z);                 // underflows to 0 for |v|>~9
  float erf_abs = fmaf(-p, e, 1.0f);
  // 0.5*v*(1+sign(v)*erf_abs) == 0.5*|v|*erf_abs + 0.5*v
  return fmaf(0.5f * a, erf_abs, 0.5f * v);
}

// ---------- gate: softmax(x @ Wg^T), one wave per token ----------
__global__ __launch_bounds__(256) void gate_kernel(
    const float* __restrict__ x, const float* __restrict__ Wg,
    float* __restrict__ gate)
{
  int t = blockIdx.x * 4 + (threadIdx.x >> 6);
  int lane = threadIdx.x & 63;
  const float* xr = x + (size_t)t * H_DIM;
  float acc[E_NUM];
#pragma unroll
  for (int e = 0; e < E_NUM; ++e) acc[e] = 0.f;
  for (int j = 0; j < H_DIM / 64; ++j) {
    float xv = xr[lane + j * 64];
#pragma unroll
    for (int e = 0; e < E_NUM; ++e)
      acc[e] += xv * Wg[e * H_DIM + lane + j * 64];
  }
#pragma unroll
  for (int e = 0; e < E_NUM; ++e)
    for (int s = 32; s > 0; s >>= 1)
      acc[e] += __shfl_xor(acc[e], s, 64);
  if (lane == 0) {
    float mx = acc[0];
#pragma unroll
    for (int e = 1; e < E_NUM; ++e) mx = fmaxf(mx, acc[e]);
    float sum = 0.f, ex[E_NUM];
#pragma unroll
    for (int e = 0; e < E_NUM; ++e) { ex[e] = expf(acc[e] - mx); sum += ex[e]; }
    float inv = 1.f / sum;
#pragma unroll
    for (int e = 0; e < E_NUM; ++e) gate[t * E_NUM + e] = ex[e] * inv;
  }
}

// ---------- x fp32 -> xb blocked bf16 [64 rb][128 kc][64][8] ----------
__global__ __launch_bounds__(256) void convert_x_kernel(
    const float* __restrict__ x, short* __restrict__ xb)
{
  int rb = blockIdx.x;                     // token/64 block
  int t  = threadIdx.x & 63;
  int kq = threadIdx.x >> 6;               // 0..3
#pragma unroll
  for (int j = 0; j < 8; ++j) {
    int kc = blockIdx.y * 32 + kq + j * 4;
    const float* src = x + ((size_t)rb * 64 + t) * H_DIM + kc * 8;
    float4 a = *(const float4*)src;
    float4 b = *(const float4*)(src + 4);
    s16x8 v;
    v[0] = f2b(a.x); v[1] = f2b(a.y); v[2] = f2b(a.z); v[3] = f2b(a.w);
    v[4] = f2b(b.x); v[5] = f2b(b.y); v[6] = f2b(b.z); v[7] = f2b(b.w);
    *(s16x8*)(xb + ((size_t)rb * 128 + kc) * 512 + t * 8) = v;
  }
}

// ---------- W1 [E][H][I] fp32 -> W1t blocked [e][rb=i/64][kc=h/8][64][8] ----------
__global__ __launch_bounds__(256) void trans_w1_kernel(
    const float* __restrict__ W1, short* __restrict__ W1t)
{
  __shared__ short tile[64][65];           // [h][i]
  int e = blockIdx.z;
  int i0 = blockIdx.x * 64, h0 = blockIdx.y * 64;
  int tid = threadIdx.x, c = tid & 63, r0 = tid >> 6;
  const float* src = W1 + ((size_t)e * H_DIM + h0) * I_DIM + i0;
#pragma unroll
  for (int j = 0; j < 16; ++j) {
    int r = j * 4 + r0;                    // h offset
    tile[r][c] = f2b(src[(size_t)r * I_DIM + c]);
  }
  __syncthreads();
  int i = tid & 63, kq = tid >> 6;
#pragma unroll
  for (int w = 0; w < 2; ++w) {
    int kcl = kq + w * 4;                  // 0..7
    s16x8 v;
#pragma unroll
    for (int j = 0; j < 8; ++j) v[j] = tile[kcl * 8 + j][i];
    size_t chunk = (size_t)e * 8192 + (size_t)blockIdx.x * 128 + (h0 >> 3) + kcl;
    *(s16x8*)(W1t + chunk * 512 + i * 8) = v;
  }
}

// ---------- W2 [E][I][H] fp32 -> W2t blocked [rb=h/64][kc=(e*I+i)/8][64][8] ----------
__global__ __launch_bounds__(256) void trans_w2_kernel(
    const float* __restrict__ W2, short* __restrict__ W2t)
{
  __shared__ short tile[64][65];           // [i][h]
  int e = blockIdx.z;
  int i0 = blockIdx.x * 64, h0 = blockIdx.y * 64;
  int tid = threadIdx.x, c = tid & 63, r0 = tid >> 6;
  const float* src = W2 + ((size_t)e * I_DIM + i0) * H_DIM + h0;
#pragma unroll
  for (int j = 0; j < 16; ++j) {
    int r = j * 4 + r0;                    // i offset
    tile[r][c] = f2b(src[(size_t)r * H_DIM + c]);
  }
  __syncthreads();
  int h = tid & 63, kq = tid >> 6;
#pragma unroll
  for (int w = 0; w < 2; ++w) {
    int kcl = kq + w * 4;                  // 0..7
    s16x8 v;
#pragma unroll
    for (int j = 0; j < 8; ++j) v[j] = tile[kcl * 8 + j][h];
    size_t chunk = (size_t)blockIdx.y * 4096 + e * 512 + (i0 >> 3) + kcl;
    *(s16x8*)(W2t + chunk * 512 + h * 8) = v;
  }
}

// ---------- out init: out[t,h] = sum_e gate[t,e] * b2[e,h] ----------
__global__ __launch_bounds__(256) void out_init_kernel(
    const float* __restrict__ gate, const float* __restrict__ b2,
    float* __restrict__ out)
{
  int idx = blockIdx.x * 256 + threadIdx.x;
  int t = idx >> 10, h = idx & 1023;
  float v = 0.f;
#pragma unroll
  for (int e = 0; e < E_NUM; ++e)
    v += gate[t * E_NUM + e] * b2[e * H_DIM + h];
  out[idx] = v;
}

// ---------- GEMM1: hg = gelu(xb @ W1t[e]^T + b1)*gate, 128x128, dbuf ----------
// launch_bounds(256,4): cap regs at 128 (64 AGPR acc + ~60 VGPR) -> 4 blocks/CU
__global__ __launch_bounds__(256, 4) void gemm1_kernel(
    const short* __restrict__ xb, const short* __restrict__ W1t,
    const float* __restrict__ b1, const float* __restrict__ gate,
    short* __restrict__ hg)
{
  __shared__ __align__(16) short As[2 * 4096];   // [buf][kcl4][128][8]
  __shared__ __align__(16) short Bs[2 * 4096];
  int bm = blockIdx.x, bn = blockIdx.y, e = blockIdx.z;

  const int tid = threadIdx.x, wave = tid >> 6, lane = tid & 63;
  const int wm = wave >> 1, wn = wave & 1;
  const int g = lane >> 4, r16 = lane & 15;

  f32x4 acc[4][4];
#pragma unroll
  for (int i = 0; i < 4; ++i)
#pragma unroll
    for (int j = 0; j < 4; ++j) acc[i][j] = (f32x4){0.f, 0.f, 0.f, 0.f};

  // staging: wave w -> chunks (rbl=w&1, kcl=w>>1) and (rbl, kcl+2) for A and B
  const int rbl = wave & 1, kq = wave >> 1;     // kq in {0,1}
  short* AsD0 = As + (kq * 128 + rbl * 64) * 8;
  short* AsD1 = As + ((kq + 2) * 128 + rbl * 64) * 8;
  short* BsD0 = Bs + (kq * 128 + rbl * 64) * 8;
  short* BsD1 = Bs + ((kq + 2) * 128 + rbl * 64) * 8;
  const short* Asrc = xb + (((size_t)(bm * 2 + rbl) * 128) + kq) * 512 + lane * 8;
  const short* Bsrc = W1t + (size_t)e * (8192 * 512)
                    + (((size_t)(bn * 2 + rbl) * 128) + kq) * 512 + lane * 8;

  // prologue: stage k-tile 0 into buf 0
  gld_lds16(AsD0, Asrc);
  gld_lds16(AsD1, Asrc + 1024);
  gld_lds16(BsD0, Bsrc);
  gld_lds16(BsD1, Bsrc + 1024);

  for (int k0 = 0; k0 < H_DIM; k0 += 32) {
    int cur = (k0 >> 5) & 1;
    __syncthreads();                       // drains prefetch issued last iter
    if (k0 + 32 < H_DIM) {
      int nb = cur ^ 1;
      size_t soff = ((size_t)(k0 >> 3) + 4) * 512;
      gld_lds16(AsD0 + nb * 4096, Asrc + soff);
      gld_lds16(AsD1 + nb * 4096, Asrc + soff + 1024);
      gld_lds16(BsD0 + nb * 4096, Bsrc + soff);
      gld_lds16(BsD1 + nb * 4096, Bsrc + soff + 1024);
    }
    const short* Ab = As + cur * 4096;
    const short* Bb = Bs + cur * 4096;
    s16x8 af[4], bfr[4];
#pragma unroll
    for (int mi = 0; mi < 4; ++mi)
      af[mi] = *(const s16x8*)(Ab + ((g << 7) + (wm << 6) + (mi << 4) + r16) * 8);
#pragma unroll
    for (int ni = 0; ni < 4; ++ni)
      bfr[ni] = *(const s16x8*)(Bb + ((g << 7) + (wn << 6) + (ni << 4) + r16) * 8);
#pragma unroll
    for (int mi = 0; mi < 4; ++mi)
#pragma unroll
      for (int ni = 0; ni < 4; ++ni)
        acc[mi][ni] = __builtin_amdgcn_mfma_f32_16x16x32_bf16(
            af[mi], bfr[ni], acc[mi][ni], 0, 0, 0);
  }

  int row0 = bm * 128 + wm * 64;
  int col0 = bn * 128 + wn * 64;
#pragma unroll
  for (int mi = 0; mi < 4; ++mi) {
#pragma unroll
    for (int r = 0; r < 4; ++r) {
      int t = row0 + mi * 16 + g * 4 + r;
      float gt = gate[t * E_NUM + e];
      size_t tbase = ((size_t)(t >> 6) * 4096) * 512 + (size_t)(t & 63) * 8;
#pragma unroll
      for (int ni = 0; ni < 4; ++ni) {
        int n = col0 + ni * 16 + r16;
        int k = e * I_DIM + n;
        float v = gelu_f(acc[mi][ni][r] + b1[e * I_DIM + n]);
        hg[tbase + (size_t)(k >> 3) * 512 + (k & 7)] = f2b(v * gt);
      }
    }
  }
}

// ---------- GEMM2: out += hg @ W2t^T ----------
// 256 threads (4 waves), tile BM=128 x BN=256, wave grid 2x2 (64x128 each),
// split-K=8 -> 1024 blocks, 48 KiB LDS, 2-3 blocks/CU resident.
__global__ __launch_bounds__(256) void gemm2_kernel(
    const short* __restrict__ hg, const short* __restrict__ W2t,
    float* __restrict__ out)
{
  __shared__ __align__(16) short As[2 * 4096];    // [buf][kq4][128][8]  16 KiB
  __shared__ __align__(16) short Bs[2 * 8192];    // [buf][kq4][256][8]  32 KiB

  int bn = blockIdx.x;        // 0..3   (fastest: consecutive blocks share A)
  int bm = blockIdx.y;        // 0..31
  int ks = blockIdx.z;        // 0..7

  const int tid = threadIdx.x, wave = tid >> 6, lane = tid & 63;
  const int wm = wave >> 1, wn = wave & 1;
  const int g = lane >> 4, r16 = lane & 15;

  f32x4 acc[4][8];
#pragma unroll
  for (int i = 0; i < 4; ++i)
#pragma unroll
    for (int j = 0; j < 8; ++j) acc[i][j] = (f32x4){0.f, 0.f, 0.f, 0.f};

  // staging: wave w handles k-group kq=w: A chunks rbl 0..1, B chunks cb 0..3
  const int kq = wave;
  short* AsD[2];
  const short* Asrc[2];
#pragma unroll
  for (int r = 0; r < 2; ++r) {
    AsD[r]  = As + (kq * 128 + r * 64) * 8;
    Asrc[r] = hg + (((size_t)(bm * 2 + r) * 4096) + kq) * 512 + lane * 8;
  }
  short* BsD[4];
  const short* Bsrc[4];
#pragma unroll
  for (int r = 0; r < 4; ++r) {
    BsD[r]  = Bs + (kq * 256 + r * 64) * 8;
    Bsrc[r] = W2t + (((size_t)(bn * 4 + r) * 4096) + kq) * 512 + lane * 8;
  }

  const int kBeg = ks * (KEI / 8), kEnd = kBeg + (KEI / 8);

  // prologue
  {
    size_t soff = (size_t)(kBeg >> 3) * 512;
#pragma unroll
    for (int r = 0; r < 2; ++r) gld_lds16(AsD[r], Asrc[r] + soff);
#pragma unroll
    for (int r = 0; r < 4; ++r) gld_lds16(BsD[r], Bsrc[r] + soff);
  }

  for (int k0 = kBeg; k0 < kEnd; k0 += 32) {
    int cur = ((k0 - kBeg) >> 5) & 1;
    __syncthreads();
    if (k0 + 32 < kEnd) {
      int nb = cur ^ 1;
      size_t soff = ((size_t)(k0 >> 3) + 4) * 512;
#pragma unroll
      for (int r = 0; r < 2; ++r) gld_lds16(AsD[r] + nb * 4096, Asrc[r] + soff);
#pragma unroll
      for (int r = 0; r < 4; ++r) gld_lds16(BsD[r] + nb * 8192, Bsrc[r] + soff);
    }
    const short* Ab = As + cur * 4096;
    const short* Bb = Bs + cur * 8192;
    s16x8 af[4], bfr[8];
#pragma unroll
    for (int mi = 0; mi < 4; ++mi)
      af[mi] = *(const s16x8*)(Ab + ((g << 7) + (wm << 6) + (mi << 4) + r16) * 8);
#pragma unroll
    for (int ni = 0; ni < 8; ++ni)
      bfr[ni] = *(const s16x8*)(Bb + ((g << 8) + (wn << 7) + (ni << 4) + r16) * 8);
#pragma unroll
    for (int mi = 0; mi < 4; ++mi)
#pragma unroll
      for (int ni = 0; ni < 8; ++ni)
        acc[mi][ni] = __builtin_amdgcn_mfma_f32_16x16x32_bf16(
            af[mi], bfr[ni], acc[mi][ni], 0, 0, 0);
  }

  int row0 = bm * 128 + wm * 64;
  int col0 = bn * 256 + wn * 128;
#pragma unroll
  for (int mi = 0; mi < 4; ++mi) {
#pragma unroll
    for (int r = 0; r < 4; ++r) {
      int t = row0 + mi * 16 + g * 4 + r;
#pragma unroll
      for (int ni = 0; ni < 8; ++ni) {
        int h = col0 + ni * 16 + r16;
        atomicAdd(&out[(size_t)t * H_DIM + h], acc[mi][ni][r]);
      }
    }
  }
}

// ---------- launch ----------
extern "C" void kernel_launch(void* const* d_in, const int* in_sizes, int n_in,
                              void* d_out, int out_size, void* d_ws, size_t ws_size,
                              hipStream_t stream) {
  const float* x  = (const float*)d_in[0];
  const float* Wg = (const float*)d_in[1];
  const float* W1 = (const float*)d_in[2];
  const float* b1 = (const float*)d_in[3];
  const float* W2 = (const float*)d_in[4];
  const float* b2 = (const float*)d_in[5];
  float* out = (float*)d_out;

  char* ws = (char*)d_ws;
  float* gate = (float*)ws;                               // 128 KiB
  short* xb   = (short*)(ws + 131072);                    // 8 MiB  (blocked)
  short* W1t  = (short*)(ws + 131072 + 8388608);          // 64 MiB (blocked)
  short* W2t  = (short*)(ws + 131072 + 8388608 + 67108864);        // 64 MiB (blocked)
  short* hg   = (short*)(ws + 131072 + 8388608 + 2 * 67108864);    // 256 MiB (blocked)

  gate_kernel<<<T_TOK / 4, 256, 0, stream>>>(x, Wg, gate);
  convert_x_kernel<<<dim3(T_TOK / 64, 4), 256, 0, stream>>>(x, xb);
  trans_w1_kernel<<<dim3(I_DIM / 64, H_DIM / 64, E_NUM), 256, 0, stream>>>(W1, W1t);
  trans_w2_kernel<<<dim3(I_DIM / 64, H_DIM / 64, E_NUM), 256, 0, stream>>>(W2, W2t);
  out_init_kernel<<<(T_TOK * H_DIM) / 256, 256, 0, stream>>>(gate, b2, out);
  gemm1_kernel<<<dim3(T_TOK / 128, I_DIM / 128, E_NUM), 256, 0, stream>>>(
      xb, W1t, b1, gate, hg);
  gemm2_kernel<<<dim3(4, 32, 8), 256, 0, stream>>>(hg, W2t, out);
}

// Round 5
// 1011.420 us; speedup vs baseline: 1.6451x; 1.0771x over previous
//
#include <hip/hip_runtime.h>
#include <math.h>

#define T_TOK 4096
#define H_DIM 1024
#define I_DIM 4096
#define E_NUM 8
#define KEI   32768   // E_NUM * I_DIM

// Blocked K-panel layout for all bf16 staged matrices:
//   M[rb][kc][64][8]  (rb = row/64, kc = k/8)
// so one global_load_lds (64 lanes x 16B) is 1KB contiguous.

typedef short s16x8 __attribute__((ext_vector_type(8)));
typedef float f32x4 __attribute__((ext_vector_type(4)));

__device__ __forceinline__ unsigned short f2b(float f) {
  union { float f; unsigned u; } v; v.f = f;
  unsigned r = v.u + 0x7fffu + ((v.u >> 16) & 1u);
  return (unsigned short)(r >> 16);
}

__device__ __forceinline__ void gld_lds16(short* lds, const short* g) {
  __builtin_amdgcn_global_load_lds(
      (const __attribute__((address_space(1))) void*)g,
      (__attribute__((address_space(3))) void*)lds, 16, 0, 0);
}

// Branch-free exact-GELU via A&S 7.1.25 3-term erf (|eps|<=2.5e-5).
__device__ __forceinline__ float gelu_f(float v) {
  float a = fabsf(v);
  float z = a * 0.70710678118f;
  float t = __builtin_amdgcn_rcpf(fmaf(0.47047f, z, 1.0f));
  float p = fmaf(fmaf(0.7478556f, t, -0.0958798f), t, 0.3480242f) * t;
  float e = __expf(-z * z);
  float erf_abs = fmaf(-p, e, 1.0f);
  // 0.5*v*(1+sign(v)*erf_abs) == 0.5*|v|*erf_abs + 0.5*v
  return fmaf(0.5f * a, erf_abs, 0.5f * v);
}

// ---------- gate: softmax(x @ Wg^T), one wave per token ----------
__global__ __launch_bounds__(256) void gate_kernel(
    const float* __restrict__ x, const float* __restrict__ Wg,
    float* __restrict__ gate)
{
  int t = blockIdx.x * 4 + (threadIdx.x >> 6);
  int lane = threadIdx.x & 63;
  const float* xr = x + (size_t)t * H_DIM;
  float acc[E_NUM];
#pragma unroll
  for (int e = 0; e < E_NUM; ++e) acc[e] = 0.f;
  for (int j = 0; j < H_DIM / 64; ++j) {
    float xv = xr[lane + j * 64];
#pragma unroll
    for (int e = 0; e < E_NUM; ++e)
      acc[e] += xv * Wg[e * H_DIM + lane + j * 64];
  }
#pragma unroll
  for (int e = 0; e < E_NUM; ++e)
    for (int s = 32; s > 0; s >>= 1)
      acc[e] += __shfl_xor(acc[e], s, 64);
  if (lane == 0) {
    float mx = acc[0];
#pragma unroll
    for (int e = 1; e < E_NUM; ++e) mx = fmaxf(mx, acc[e]);
    float sum = 0.f, ex[E_NUM];
#pragma unroll
    for (int e = 0; e < E_NUM; ++e) { ex[e] = expf(acc[e] - mx); sum += ex[e]; }
    float inv = 1.f / sum;
#pragma unroll
    for (int e = 0; e < E_NUM; ++e) gate[t * E_NUM + e] = ex[e] * inv;
  }
}

// ---------- x fp32 -> xb blocked bf16 [64 rb][128 kc][64][8] ----------
__global__ __launch_bounds__(256) void convert_x_kernel(
    const float* __restrict__ x, short* __restrict__ xb)
{
  int rb = blockIdx.x;                     // token/64 block
  int t  = threadIdx.x & 63;
  int kq = threadIdx.x >> 6;               // 0..3
#pragma unroll
  for (int j = 0; j < 8; ++j) {
    int kc = blockIdx.y * 32 + kq + j * 4;
    const float* src = x + ((size_t)rb * 64 + t) * H_DIM + kc * 8;
    float4 a = *(const float4*)src;
    float4 b = *(const float4*)(src + 4);
    s16x8 v;
    v[0] = f2b(a.x); v[1] = f2b(a.y); v[2] = f2b(a.z); v[3] = f2b(a.w);
    v[4] = f2b(b.x); v[5] = f2b(b.y); v[6] = f2b(b.z); v[7] = f2b(b.w);
    *(s16x8*)(xb + ((size_t)rb * 128 + kc) * 512 + t * 8) = v;
  }
}

// ---------- W1 [E][H][I] fp32 -> W1t blocked [e][rb=i/64][kc=h/8][64][8] ----------
__global__ __launch_bounds__(256) void trans_w1_kernel(
    const float* __restrict__ W1, short* __restrict__ W1t)
{
  __shared__ short tile[64][65];           // [h][i]
  int e = blockIdx.z;
  int i0 = blockIdx.x * 64, h0 = blockIdx.y * 64;
  int tid = threadIdx.x, c = tid & 63, r0 = tid >> 6;
  const float* src = W1 + ((size_t)e * H_DIM + h0) * I_DIM + i0;
#pragma unroll
  for (int j = 0; j < 16; ++j) {
    int r = j * 4 + r0;                    // h offset
    tile[r][c] = f2b(src[(size_t)r * I_DIM + c]);
  }
  __syncthreads();
  int i = tid & 63, kq = tid >> 6;
#pragma unroll
  for (int w = 0; w < 2; ++w) {
    int kcl = kq + w * 4;                  // 0..7
    s16x8 v;
#pragma unroll
    for (int j = 0; j < 8; ++j) v[j] = tile[kcl * 8 + j][i];
    size_t chunk = (size_t)e * 8192 + (size_t)blockIdx.x * 128 + (h0 >> 3) + kcl;
    *(s16x8*)(W1t + chunk * 512 + i * 8) = v;
  }
}

// ---------- W2 [E][I][H] fp32 -> W2t blocked [rb=h/64][kc=(e*I+i)/8][64][8] ----------
__global__ __launch_bounds__(256) void trans_w2_kernel(
    const float* __restrict__ W2, short* __restrict__ W2t)
{
  __shared__ short tile[64][65];           // [i][h]
  int e = blockIdx.z;
  int i0 = blockIdx.x * 64, h0 = blockIdx.y * 64;
  int tid = threadIdx.x, c = tid & 63, r0 = tid >> 6;
  const float* src = W2 + ((size_t)e * I_DIM + i0) * H_DIM + h0;
#pragma unroll
  for (int j = 0; j < 16; ++j) {
    int r = j * 4 + r0;                    // i offset
    tile[r][c] = f2b(src[(size_t)r * H_DIM + c]);
  }
  __syncthreads();
  int h = tid & 63, kq = tid >> 6;
#pragma unroll
  for (int w = 0; w < 2; ++w) {
    int kcl = kq + w * 4;                  // 0..7
    s16x8 v;
#pragma unroll
    for (int j = 0; j < 8; ++j) v[j] = tile[kcl * 8 + j][h];
    size_t chunk = (size_t)blockIdx.y * 4096 + e * 512 + (i0 >> 3) + kcl;
    *(s16x8*)(W2t + chunk * 512 + h * 8) = v;
  }
}

// ---------- out init: out[t,h] = sum_e gate[t,e] * b2[e,h] ----------
__global__ __launch_bounds__(256) void out_init_kernel(
    const float* __restrict__ gate, const float* __restrict__ b2,
    float* __restrict__ out)
{
  int idx = blockIdx.x * 256 + threadIdx.x;
  int t = idx >> 10, h = idx & 1023;
  float v = 0.f;
#pragma unroll
  for (int e = 0; e < E_NUM; ++e)
    v += gate[t * E_NUM + e] * b2[e * H_DIM + h];
  out[idx] = v;
}

// ---------- GEMM1: hg^T path. A-operand = W1 tile, B-operand = x tile ----------
// Computes D[n][t] so each lane holds 4 CONSECUTIVE n for one token ->
// 8B packed stores into blocked hg, float4 b1 loads, 4 gate loads/thread.
__global__ __launch_bounds__(256, 4) void gemm1_kernel(
    const short* __restrict__ xb, const short* __restrict__ W1t,
    const float* __restrict__ b1, const float* __restrict__ gate,
    short* __restrict__ hg)
{
  __shared__ __align__(16) short As[2 * 4096];   // x tile    [buf][kcl4][128][8]
  __shared__ __align__(16) short Bs[2 * 4096];   // W1 tile
  int bm = blockIdx.x, bn = blockIdx.y, e = blockIdx.z;

  const int tid = threadIdx.x, wave = tid >> 6, lane = tid & 63;
  const int wm = wave >> 1, wn = wave & 1;
  const int g = lane >> 4, r16 = lane & 15;

  f32x4 acc[4][4];
#pragma unroll
  for (int i = 0; i < 4; ++i)
#pragma unroll
    for (int j = 0; j < 4; ++j) acc[i][j] = (f32x4){0.f, 0.f, 0.f, 0.f};

  // staging: wave w -> chunks (rbl=w&1, kcl=w>>1) and (rbl, kcl+2) for A and B
  const int rbl = wave & 1, kq = wave >> 1;     // kq in {0,1}
  short* AsD0 = As + (kq * 128 + rbl * 64) * 8;
  short* AsD1 = As + ((kq + 2) * 128 + rbl * 64) * 8;
  short* BsD0 = Bs + (kq * 128 + rbl * 64) * 8;
  short* BsD1 = Bs + ((kq + 2) * 128 + rbl * 64) * 8;
  const short* Asrc = xb + (((size_t)(bm * 2 + rbl) * 128) + kq) * 512 + lane * 8;
  const short* Bsrc = W1t + (size_t)e * (8192 * 512)
                    + (((size_t)(bn * 2 + rbl) * 128) + kq) * 512 + lane * 8;

  // prologue: stage k-tile 0 into buf 0
  gld_lds16(AsD0, Asrc);
  gld_lds16(AsD1, Asrc + 1024);
  gld_lds16(BsD0, Bsrc);
  gld_lds16(BsD1, Bsrc + 1024);

  for (int k0 = 0; k0 < H_DIM; k0 += 32) {
    int cur = (k0 >> 5) & 1;
    __syncthreads();                       // drains prefetch issued last iter
    if (k0 + 32 < H_DIM) {
      int nb = cur ^ 1;
      size_t soff = ((size_t)(k0 >> 3) + 4) * 512;
      gld_lds16(AsD0 + nb * 4096, Asrc + soff);
      gld_lds16(AsD1 + nb * 4096, Asrc + soff + 1024);
      gld_lds16(BsD0 + nb * 4096, Bsrc + soff);
      gld_lds16(BsD1 + nb * 4096, Bsrc + soff + 1024);
    }
    const short* Ab = As + cur * 4096;
    const short* Bb = Bs + cur * 4096;
    s16x8 af[4], bfr[4];
    // A-operand = W1 rows (n), indexed by wm; B-operand = tokens, indexed by wn
#pragma unroll
    for (int mi = 0; mi < 4; ++mi)
      af[mi] = *(const s16x8*)(Bb + ((g << 7) + (wm << 6) + (mi << 4) + r16) * 8);
#pragma unroll
    for (int ni = 0; ni < 4; ++ni)
      bfr[ni] = *(const s16x8*)(Ab + ((g << 7) + (wn << 6) + (ni << 4) + r16) * 8);
#pragma unroll
    for (int mi = 0; mi < 4; ++mi)
#pragma unroll
      for (int ni = 0; ni < 4; ++ni)
        acc[mi][ni] = __builtin_amdgcn_mfma_f32_16x16x32_bf16(
            af[mi], bfr[ni], acc[mi][ni], 0, 0, 0);
  }

  // D[row = n (W1 side)][col = t (x side)]
  int n_base0 = bn * 128 + wm * 64;          // i-dim base for this wave
  int t_base  = bm * 128 + wn * 64;          // token base for this wave
  float gt[4];
#pragma unroll
  for (int ni = 0; ni < 4; ++ni)
    gt[ni] = gate[(t_base + ni * 16 + r16) * E_NUM + e];
#pragma unroll
  for (int mi = 0; mi < 4; ++mi) {
    int nb = n_base0 + mi * 16 + g * 4;      // 4 consecutive n
    float4 b1v = *(const float4*)(b1 + e * I_DIM + nb);
    int k = e * I_DIM + nb;
    size_t koff = (size_t)(k >> 3) * 512 + (k & 7);
#pragma unroll
    for (int ni = 0; ni < 4; ++ni) {
      int t = t_base + ni * 16 + r16;
      float v0 = gelu_f(acc[mi][ni][0] + b1v.x) * gt[ni];
      float v1 = gelu_f(acc[mi][ni][1] + b1v.y) * gt[ni];
      float v2 = gelu_f(acc[mi][ni][2] + b1v.z) * gt[ni];
      float v3 = gelu_f(acc[mi][ni][3] + b1v.w) * gt[ni];
      int2 pk;
      pk.x = (int)((unsigned)f2b(v0) | ((unsigned)f2b(v1) << 16));
      pk.y = (int)((unsigned)f2b(v2) | ((unsigned)f2b(v3) << 16));
      *(int2*)(hg + (size_t)(t >> 6) * (4096 * 512) + koff + (size_t)(t & 63) * 8) = pk;
    }
  }
}

// ---------- GEMM2: out += hg @ W2t^T ----------
// 256 threads (4 waves), tile BM=128 x BN=256, wave grid 2x2 (64x128 each),
// split-K=8 -> 1024 blocks, 48 KiB LDS.
__global__ __launch_bounds__(256) void gemm2_kernel(
    const short* __restrict__ hg, const short* __restrict__ W2t,
    float* __restrict__ out)
{
  __shared__ __align__(16) short As[2 * 4096];    // [buf][kq4][128][8]  16 KiB
  __shared__ __align__(16) short Bs[2 * 8192];    // [buf][kq4][256][8]  32 KiB

  int bn = blockIdx.x;        // 0..3   (fastest: consecutive blocks share A)
  int bm = blockIdx.y;        // 0..31
  int ks = blockIdx.z;        // 0..7

  const int tid = threadIdx.x, wave = tid >> 6, lane = tid & 63;
  const int wm = wave >> 1, wn = wave & 1;
  const int g = lane >> 4, r16 = lane & 15;

  f32x4 acc[4][8];
#pragma unroll
  for (int i = 0; i < 4; ++i)
#pragma unroll
    for (int j = 0; j < 8; ++j) acc[i][j] = (f32x4){0.f, 0.f, 0.f, 0.f};

  // staging: wave w handles k-group kq=w: A chunks rbl 0..1, B chunks cb 0..3
  const int kq = wave;
  short* AsD[2];
  const short* Asrc[2];
#pragma unroll
  for (int r = 0; r < 2; ++r) {
    AsD[r]  = As + (kq * 128 + r * 64) * 8;
    Asrc[r] = hg + (((size_t)(bm * 2 + r) * 4096) + kq) * 512 + lane * 8;
  }
  short* BsD[4];
  const short* Bsrc[4];
#pragma unroll
  for (int r = 0; r < 4; ++r) {
    BsD[r]  = Bs + (kq * 256 + r * 64) * 8;
    Bsrc[r] = W2t + (((size_t)(bn * 4 + r) * 4096) + kq) * 512 + lane * 8;
  }

  const int kBeg = ks * (KEI / 8), kEnd = kBeg + (KEI / 8);

  // prologue
  {
    size_t soff = (size_t)(kBeg >> 3) * 512;
#pragma unroll
    for (int r = 0; r < 2; ++r) gld_lds16(AsD[r], Asrc[r] + soff);
#pragma unroll
    for (int r = 0; r < 4; ++r) gld_lds16(BsD[r], Bsrc[r] + soff);
  }

  for (int k0 = kBeg; k0 < kEnd; k0 += 32) {
    int cur = ((k0 - kBeg) >> 5) & 1;
    __syncthreads();
    if (k0 + 32 < kEnd) {
      int nb = cur ^ 1;
      size_t soff = ((size_t)(k0 >> 3) + 4) * 512;
#pragma unroll
      for (int r = 0; r < 2; ++r) gld_lds16(AsD[r] + nb * 4096, Asrc[r] + soff);
#pragma unroll
      for (int r = 0; r < 4; ++r) gld_lds16(BsD[r] + nb * 8192, Bsrc[r] + soff);
    }
    const short* Ab = As + cur * 4096;
    const short* Bb = Bs + cur * 8192;
    s16x8 af[4], bfr[8];
#pragma unroll
    for (int mi = 0; mi < 4; ++mi)
      af[mi] = *(const s16x8*)(Ab + ((g << 7) + (wm << 6) + (mi << 4) + r16) * 8);
#pragma unroll
    for (int ni = 0; ni < 8; ++ni)
      bfr[ni] = *(const s16x8*)(Bb + ((g << 8) + (wn << 7) + (ni << 4) + r16) * 8);
#pragma unroll
    for (int mi = 0; mi < 4; ++mi)
#pragma unroll
      for (int ni = 0; ni < 8; ++ni)
        acc[mi][ni] = __builtin_amdgcn_mfma_f32_16x16x32_bf16(
            af[mi], bfr[ni], acc[mi][ni], 0, 0, 0);
  }

  int row0 = bm * 128 + wm * 64;
  int col0 = bn * 256 + wn * 128;
#pragma unroll
  for (int mi = 0; mi < 4; ++mi) {
#pragma unroll
    for (int r = 0; r < 4; ++r) {
      int t = row0 + mi * 16 + g * 4 + r;
#pragma unroll
      for (int ni = 0; ni < 8; ++ni) {
        int h = col0 + ni * 16 + r16;
        atomicAdd(&out[(size_t)t * H_DIM + h], acc[mi][ni][r]);
      }
    }
  }
}

// ---------- launch ----------
extern "C" void kernel_launch(void* const* d_in, const int* in_sizes, int n_in,
                              void* d_out, int out_size, void* d_ws, size_t ws_size,
                              hipStream_t stream) {
  const float* x  = (const float*)d_in[0];
  const float* Wg = (const float*)d_in[1];
  const float* W1 = (const float*)d_in[2];
  const float* b1 = (const float*)d_in[3];
  const float* W2 = (const float*)d_in[4];
  const float* b2 = (const float*)d_in[5];
  float* out = (float*)d_out;

  char* ws = (char*)d_ws;
  float* gate = (float*)ws;                               // 128 KiB
  short* xb   = (short*)(ws + 131072);                    // 8 MiB  (blocked)
  short* W1t  = (short*)(ws + 131072 + 8388608);          // 64 MiB (blocked)
  short* W2t  = (short*)(ws + 131072 + 8388608 + 67108864);        // 64 MiB (blocked)
  short* hg   = (short*)(ws + 131072 + 8388608 + 2 * 67108864);    // 256 MiB (blocked)

  gate_kernel<<<T_TOK / 4, 256, 0, stream>>>(x, Wg, gate);
  convert_x_kernel<<<dim3(T_TOK / 64, 4), 256, 0, stream>>>(x, xb);
  trans_w1_kernel<<<dim3(I_DIM / 64, H_DIM / 64, E_NUM), 256, 0, stream>>>(W1, W1t);
  trans_w2_kernel<<<dim3(I_DIM / 64, H_DIM / 64, E_NUM), 256, 0, stream>>>(W2, W2t);
  out_init_kernel<<<(T_TOK * H_DIM) / 256, 256, 0, stream>>>(gate, b2, out);
  gemm1_kernel<<<dim3(T_TOK / 128, I_DIM / 128, E_NUM), 256, 0, stream>>>(
      xb, W1t, b1, gate, hg);
  gemm2_kernel<<<dim3(4, 32, 8), 256, 0, stream>>>(hg, W2t, out);
}